// Round 5
// baseline (389.668 us; speedup 1.0000x reference)
//
#include <hip/hip_runtime.h>
#include <hip/hip_cooperative_groups.h>
#include <math.h>

namespace cg = cooperative_groups;

// Problem constants (from reference setup_inputs)
#define BATCH 512
#define LEN   16384
#define WIN   5
#define WOUT  (LEN - WIN + 1)   // 16380
#define TPB   256
#define WPT   4                  // windows per thread (WOUT % WPT == 0)
#define WPB   (TPB * WPT)        // 1024 windows per block
#define EPT   (WPT + WIN - 1)    // 8 elements per thread
#define WBLKS ((WOUT + WPB - 1) / WPB)   // 16 window-column blocks
#define RWGS  ((WOUT + TPB - 1) / TPB)   // 64 reduce WGs (phase 2)
#define NCH2  16                 // fallback-path stage-A groups

// fast reciprocal: v_rcp_f32 + 1 Newton step, ~3 insts vs ~10 for fdiv
__device__ __forceinline__ float fast_rcp(float x) {
    float r = __builtin_amdgcn_rcpf(x);
    return r * fmaf(-x, r, 2.0f);
}

struct RowRaw {
    int4   m0, m1, t0, t1;
    float4 q0, q1, q2, q3;
};
struct RowArr {
    float m[EPT], tm[EPT], pm[EPT], p2m[EPT];
};

__device__ __forceinline__ RowRaw load_row(const float* __restrict__ pred,
                                           const int*   __restrict__ tgt,
                                           const int*   __restrict__ msk,
                                           size_t base) {
    RowRaw r;
    r.m0 = *(const int4*)(msk + base);
    r.m1 = *(const int4*)(msk + base + 4);
    r.t0 = *(const int4*)(tgt + base);
    r.t1 = *(const int4*)(tgt + base + 4);
    r.q0 = *(const float4*)(pred + base * 2);
    r.q1 = *(const float4*)(pred + base * 2 + 4);
    r.q2 = *(const float4*)(pred + base * 2 + 8);
    r.q3 = *(const float4*)(pred + base * 2 + 12);
    return r;
}

// Same per-element arithmetic as the verified round-2/4 kernels.
__device__ __forceinline__ RowArr convert_row(const RowRaw& r) {
    RowArr a;
    const int mi[EPT] = {r.m0.x, r.m0.y, r.m0.z, r.m0.w,
                         r.m1.x, r.m1.y, r.m1.z, r.m1.w};
    const int ti[EPT] = {r.t0.x, r.t0.y, r.t0.z, r.t0.w,
                         r.t1.x, r.t1.y, r.t1.z, r.t1.w};
    const float dx[EPT] = {r.q0.x - r.q0.y, r.q0.z - r.q0.w,
                           r.q1.x - r.q1.y, r.q1.z - r.q1.w,
                           r.q2.x - r.q2.y, r.q2.z - r.q2.w,
                           r.q3.x - r.q3.y, r.q3.z - r.q3.w};
#pragma unroll
    for (int i = 0; i < EPT; ++i) {
        const float p  = fast_rcp(1.0f + __expf(dx[i]));  // softmax[...,1]
        const float mf = (float)mi[i];
        a.m[i]   = mf;
        a.tm[i]  = (float)(ti[i] & mi[i]);  // t*m, both in {0,1}
        a.pm[i]  = p * mf;
        a.p2m[i] = p * p * mf;
    }
    return a;
}

// Same window math & ascending tap order -> bit-identical partials.
__device__ __forceinline__ void windows_row(const RowArr& a,
                                            float accd2[WPT], float accms[WPT]) {
#pragma unroll
    for (int w = 0; w < WPT; ++w) {
        float msum = 0.f, stm = 0.f, spm = 0.f, sp2m = 0.f;
#pragma unroll
        for (int k = 0; k < WIN; ++k) {
            msum += a.m[w + k];
            stm  += a.tm[w + k];
            spm  += a.pm[w + k];
            sp2m += a.p2m[w + k];
        }
        // st2m == stm since t in {0,1}
        const float denom = fmaxf(msum, 1.0f);
        const float inv   = fast_rcp(denom);
        const float pmean = spm * inv;
        const float tmean = stm * inv;
        const float pvar  = (sp2m - 2.0f * pmean * spm + pmean * pmean * msum) * inv;
        const float tvar  = (stm  - 2.0f * tmean * stm + tmean * tmean * msum) * inv;
        const float d = pvar - tvar;
        accd2[w] += d * d;
        accms[w] += msum;
    }
}

// Per-thread partial phase (shared by fused + fallback kernels).
__device__ __forceinline__ void partial_phase(const float* __restrict__ pred,
                                              const int*   __restrict__ tgt,
                                              const int*   __restrict__ msk,
                                              float* __restrict__ part_d2,
                                              float* __restrict__ part_ms,
                                              int col, int chunk, int bper) {
    const int j0 = col * WPB + (int)threadIdx.x * WPT;  // first window
    if (j0 >= WOUT) return;   // inlined into an if-guard at fused call site
    const int b0 = chunk * bper;

    float accd2[WPT] = {0.f, 0.f, 0.f, 0.f};
    float accms[WPT] = {0.f, 0.f, 0.f, 0.f};

    size_t base = (size_t)b0 * LEN + j0;  // j0 % 4 == 0 -> 16B aligned
    for (int it = 0; it < bper; ++it) {   // ascending b: deterministic
        RowRaw raw = load_row(pred, tgt, msk, base + (size_t)it * LEN);
        RowArr arr = convert_row(raw);
        windows_row(arr, accd2, accms);
    }

    *(float4*)(part_d2 + (size_t)chunk * WOUT + j0) =
        make_float4(accd2[0], accd2[1], accd2[2], accd2[3]);
    *(float4*)(part_ms + (size_t)chunk * WOUT + j0) =
        make_float4(accms[0], accms[1], accms[2], accms[3]);
}

// ---------------- Fused single-dispatch cooperative kernel ----------------
// Phase 1: partials (grid = WBLKS x nchunks flattened, <=1024 WGs -> safely
// co-resident at 4 WGs/CU). grid.sync(). Phase 2: WGs 0..RWGS-1 fold chunks
// per window (ascending c), gate ms>0, reduce to doubles, atomicAdd.
// grid.sync(). Phase 3: WG 0 finalizes. NO early returns before grid.sync().
__global__ __launch_bounds__(TPB)
void bcl_fused(const float* __restrict__ pred,
               const int*   __restrict__ tgt,
               const int*   __restrict__ msk,
               float* __restrict__ part_d2,
               float* __restrict__ part_ms,
               double* __restrict__ accum,   // [num, cnt]
               float* __restrict__ out,
               int nchunks, int bper) {
    cg::grid_group grid = cg::this_grid();
    const int wg    = blockIdx.x;
    const int col   = wg & (WBLKS - 1);   // WBLKS = 16 (pow2)
    const int chunk = wg >> 4;

    if (wg == 0 && threadIdx.x == 0) { accum[0] = 0.0; accum[1] = 0.0; }

    partial_phase(pred, tgt, msk, part_d2, part_ms, col, chunk, bper);

    grid.sync();

    if (wg < RWGS) {
        const int j = wg * TPB + (int)threadIdx.x;
        double num = 0.0, cnt = 0.0;
        if (j < WOUT) {
            float d2 = 0.f, ms = 0.f;
#pragma unroll 8
            for (int c = 0; c < nchunks; ++c) {   // ascending c: deterministic
                d2 += part_d2[(size_t)c * WOUT + j];
                ms += part_ms[(size_t)c * WOUT + j];
            }
            if (ms > 0.f) {
                num = (double)d2 * (1.0 / (double)BATCH);
                cnt = 1.0;
            }
        }
        // wave reduce (wave = 64)
        for (int off = 32; off > 0; off >>= 1) {
            num += __shfl_down(num, off, 64);
            cnt += __shfl_down(cnt, off, 64);
        }
        __shared__ double s_num[4], s_cnt[4];
        const int lane = threadIdx.x & 63, wave = threadIdx.x >> 6;
        if (lane == 0) { s_num[wave] = num; s_cnt[wave] = cnt; }
        __syncthreads();          // uniform within participating WGs
        if (threadIdx.x == 0) {
            double n = 0.0, c = 0.0;
            for (int wv = 0; wv < TPB / 64; ++wv) { n += s_num[wv]; c += s_cnt[wv]; }
            atomicAdd(&accum[0], n);
            atomicAdd(&accum[1], c);
            __threadfence();
        }
    }

    grid.sync();

    if (wg == 0 && threadIdx.x == 0) {
        out[0] = (float)(accum[0] / fmax(accum[1], 1.0));
    }
}

// ---------------- Fallback path (proven round-4 3-kernel chain) ----------------
__global__ __launch_bounds__(TPB)
void bcl_partial_kernel(const float* __restrict__ pred,
                        const int*   __restrict__ tgt,
                        const int*   __restrict__ msk,
                        float* __restrict__ part_d2,
                        float* __restrict__ part_ms,
                        int bper) {
    partial_phase(pred, tgt, msk, part_d2, part_ms, blockIdx.x, blockIdx.y, bper);
}

__global__ __launch_bounds__(TPB)
void bcl_chunk_reduce(const float* __restrict__ part_d2,
                      const float* __restrict__ part_ms,
                      float* __restrict__ p2_d2,
                      float* __restrict__ p2_ms,
                      double* __restrict__ accum,
                      unsigned int* __restrict__ ticket,
                      int rf) {
    if (blockIdx.x == 0 && blockIdx.y == 0 && threadIdx.x == 0) {
        accum[0] = 0.0; accum[1] = 0.0; *ticket = 0u;
    }
    const int j = blockIdx.x * blockDim.x + threadIdx.x;
    if (j >= WOUT) return;
    const int c0 = blockIdx.y * rf;
    float d2 = 0.f, ms = 0.f;
#pragma unroll 8
    for (int c = c0; c < c0 + rf; ++c) {
        d2 += part_d2[(size_t)c * WOUT + j];
        ms += part_ms[(size_t)c * WOUT + j];
    }
    p2_d2[(size_t)blockIdx.y * WOUT + j] = d2;
    p2_ms[(size_t)blockIdx.y * WOUT + j] = ms;
}

__global__ __launch_bounds__(TPB)
void bcl_window_reduce(const float* __restrict__ p2_d2,
                       const float* __restrict__ p2_ms,
                       double* __restrict__ accum,
                       unsigned int* __restrict__ ticket,
                       float* __restrict__ out,
                       int nch2) {
    const int j = blockIdx.x * blockDim.x + threadIdx.x;
    double num = 0.0, cnt = 0.0;
    if (j < WOUT) {
        float d2 = 0.f, ms = 0.f;
#pragma unroll 8
        for (int c = 0; c < nch2; ++c) {
            d2 += p2_d2[(size_t)c * WOUT + j];
            ms += p2_ms[(size_t)c * WOUT + j];
        }
        if (ms > 0.f) {
            num = (double)d2 * (1.0 / (double)BATCH);
            cnt = 1.0;
        }
    }
    for (int off = 32; off > 0; off >>= 1) {
        num += __shfl_down(num, off, 64);
        cnt += __shfl_down(cnt, off, 64);
    }
    __shared__ double s_num[4], s_cnt[4];
    const int lane = threadIdx.x & 63, wave = threadIdx.x >> 6;
    if (lane == 0) { s_num[wave] = num; s_cnt[wave] = cnt; }
    __syncthreads();
    if (threadIdx.x == 0) {
        double n = 0.0, c = 0.0;
        for (int wv = 0; wv < TPB / 64; ++wv) { n += s_num[wv]; c += s_cnt[wv]; }
        atomicAdd(&accum[0], n);
        atomicAdd(&accum[1], c);
        __threadfence();
        const unsigned int t = atomicAdd(ticket, 1u);
        if (t == gridDim.x - 1) {
            out[0] = (float)(accum[0] / fmax(accum[1], 1.0));
        }
    }
}

extern "C" void kernel_launch(void* const* d_in, const int* in_sizes, int n_in,
                              void* d_out, int out_size, void* d_ws, size_t ws_size,
                              hipStream_t stream) {
    const float* pred = (const float*)d_in[0];
    const int*   tgt  = (const int*)d_in[1];
    const int*   msk  = (const int*)d_in[2];
    float* out = (float*)d_out;

    // nchunks: <=64 keeps coop grid <=1024 WGs (half of guaranteed residency).
    int nchunks = 64;
    while (nchunks > 2) {
        size_t need = (size_t)(nchunks + NCH2) * WOUT * 2 * sizeof(float) + 256;
        if (need <= ws_size) break;
        nchunks >>= 1;
    }
    const int bper = BATCH / nchunks;

    float* part_d2 = (float*)d_ws;
    float* part_ms = part_d2 + (size_t)nchunks * WOUT;
    float* p2_d2   = part_ms + (size_t)nchunks * WOUT;   // fallback only
    float* p2_ms   = p2_d2   + (size_t)NCH2 * WOUT;      // fallback only
    size_t off = ((size_t)((char*)(p2_ms + (size_t)NCH2 * WOUT) - (char*)d_ws) + 15) & ~(size_t)15;
    double* accum = (double*)((char*)d_ws + off);
    unsigned int* ticket = (unsigned int*)(accum + 2);

    // ---- primary: single cooperative dispatch ----
    dim3 gF(WBLKS * nchunks);  // <= 1024
    int nck = nchunks, bp = bper;
    void* args[] = { (void*)&pred, (void*)&tgt, (void*)&msk,
                     (void*)&part_d2, (void*)&part_ms,
                     (void*)&accum, (void*)&out, (void*)&nck, (void*)&bp };
    hipError_t e = hipLaunchCooperativeKernel((const void*)bcl_fused, gF, dim3(TPB),
                                              args, 0, stream);
    if (e == hipSuccess) return;
    (void)hipGetLastError();   // clear sticky error, fall back

    // ---- fallback: proven 3-kernel chain ----
    const int nch2 = (nchunks >= NCH2) ? NCH2 : nchunks;
    const int rf   = nchunks / nch2;
    dim3 g1(WBLKS, nchunks);
    bcl_partial_kernel<<<g1, TPB, 0, stream>>>(pred, tgt, msk, part_d2, part_ms, bper);
    dim3 gA(RWGS, nch2);
    bcl_chunk_reduce<<<gA, TPB, 0, stream>>>(part_d2, part_ms, p2_d2, p2_ms,
                                             accum, ticket, rf);
    bcl_window_reduce<<<RWGS, TPB, 0, stream>>>(p2_d2, p2_ms, accum, ticket, out, nch2);
}

// Round 6
// 167.224 us; speedup vs baseline: 2.3302x; 2.3302x over previous
//
#include <hip/hip_runtime.h>
#include <math.h>

// Problem constants (from reference setup_inputs)
#define BATCH 512
#define LEN   16384
#define WIN   5
#define WOUT  (LEN - WIN + 1)   // 16380
#define TPB   256
#define WPT   4                  // windows per thread (WOUT % WPT == 0)
#define WPB   (TPB * WPT)        // 1024 windows per block
#define EPT   (WPT + WIN - 1)    // 8 elements per thread
#define WBLKS ((WOUT + WPB - 1) / WPB)   // 16 window-column blocks
#define RWGS  ((WOUT + TPB - 1) / TPB)   // 64 reduce blocks
#define NCH2  16                 // stage-A output chunk groups

// LDS tile layout (per buffer): [mask 5KB][tgt 5KB][pred 9KB] = 19456 B.
// Staged as 1KB units (64 lanes x 16B) via global_load_lds.
#define LBUF   19456
#define MT_ISS 5                 // 1KB issues for mask (and tgt): 1028*4B -> 5
#define PR_ISS 9                 // 1KB issues for pred: 1028*8B -> 9
#define N_ISS  (2 * MT_ISS + PR_ISS)   // 19 issues per row per WG

// fast reciprocal: v_rcp_f32 + 1 Newton step, ~3 insts vs ~10 for fdiv
__device__ __forceinline__ float fast_rcp(float x) {
    float r = __builtin_amdgcn_rcpf(x);
    return r * fmaf(-x, r, 2.0f);
}

struct RowRaw {
    int4   m0, m1, t0, t1;
    float4 q0, q1, q2, q3;
};
struct RowArr {
    float m[EPT], tm[EPT], pm[EPT], p2m[EPT];
};

// Same per-element arithmetic as the verified round-2/4 kernels.
__device__ __forceinline__ RowArr convert_row(const RowRaw& r) {
    RowArr a;
    const int mi[EPT] = {r.m0.x, r.m0.y, r.m0.z, r.m0.w,
                         r.m1.x, r.m1.y, r.m1.z, r.m1.w};
    const int ti[EPT] = {r.t0.x, r.t0.y, r.t0.z, r.t0.w,
                         r.t1.x, r.t1.y, r.t1.z, r.t1.w};
    const float dx[EPT] = {r.q0.x - r.q0.y, r.q0.z - r.q0.w,
                           r.q1.x - r.q1.y, r.q1.z - r.q1.w,
                           r.q2.x - r.q2.y, r.q2.z - r.q2.w,
                           r.q3.x - r.q3.y, r.q3.z - r.q3.w};
#pragma unroll
    for (int i = 0; i < EPT; ++i) {
        const float p  = fast_rcp(1.0f + __expf(dx[i]));  // softmax[...,1]
        const float mf = (float)mi[i];
        a.m[i]   = mf;
        a.tm[i]  = (float)(ti[i] & mi[i]);  // t*m, both in {0,1}
        a.pm[i]  = p * mf;
        a.p2m[i] = p * p * mf;
    }
    return a;
}

// Same window math & ascending tap order -> bit-identical partials.
__device__ __forceinline__ void windows_row(const RowArr& a,
                                            float accd2[WPT], float accms[WPT]) {
#pragma unroll
    for (int w = 0; w < WPT; ++w) {
        float msum = 0.f, stm = 0.f, spm = 0.f, sp2m = 0.f;
#pragma unroll
        for (int k = 0; k < WIN; ++k) {
            msum += a.m[w + k];
            stm  += a.tm[w + k];
            spm  += a.pm[w + k];
            sp2m += a.p2m[w + k];
        }
        // st2m == stm since t in {0,1}
        const float denom = fmaxf(msum, 1.0f);
        const float inv   = fast_rcp(denom);
        const float pmean = spm * inv;
        const float tmean = stm * inv;
        const float pvar  = (sp2m - 2.0f * pmean * spm + pmean * pmean * msum) * inv;
        const float tvar  = (stm  - 2.0f * tmean * stm + tmean * tmean * msum) * inv;
        const float d = pvar - tvar;
        accd2[w] += d * d;
        accms[w] += msum;
    }
}

// Kernel 1: async global->LDS staging (global_load_lds, width 16) with a
// 2-deep LDS double buffer. Loads consume NO VGPRs -> each WG keeps 19KB in
// flight per row independent of register allocation (the thing the compiler
// refused to do in rounds 2-4: it pinned VGPR at 32-36 and serialized ~4
// waited load groups per row). 4 WGs/CU (LDS-limited) x 19KB ~= 76KB in
// flight per CU -> latency fully covered, HBM-issue bound.
__global__ __launch_bounds__(TPB)
void bcl_partial_staged(const float* __restrict__ pred,
                        const int*   __restrict__ tgt,
                        const int*   __restrict__ msk,
                        float* __restrict__ part_d2,
                        float* __restrict__ part_ms,
                        int bper) {
    __shared__ __align__(1024) char s_lds[2 * LBUF];
    const int col   = blockIdx.x;          // 0..WBLKS-1
    const int chunk = blockIdx.y;
    const int tid   = (int)threadIdx.x;
    const int lane  = tid & 63, wid = tid >> 6;
    const int j0    = col * WPB + tid * WPT;   // first window owned
    const int b0    = chunk * bper;

    const char* mbytes = (const char*)msk;
    const char* tbytes = (const char*)tgt;
    const char* pbytes = (const char*)pred;
    const int cmt = col * (WPB * 4);   // mask/tgt tile byte offset in row
    const int cpr = col * (WPB * 8);   // pred tile byte offset in row

    // Stage one batch-row's tile into LDS buffer `buf`. Issues are 1KB
    // (64 lanes x 16B), distributed across the 4 waves; LDS dest is the
    // wave-uniform base (HW adds lane*16); global src is per-lane.
    // Tail issues are clamped to stay inside the row (duplicate bytes land
    // in never-read halo slots).
    auto stage = [&](char* buf, int b) {
        const char* mrow = mbytes + (size_t)b * (LEN * 4);
        const char* trow = tbytes + (size_t)b * (LEN * 4);
        const char* prow = pbytes + (size_t)b * (LEN * 8);
        for (int i = wid; i < N_ISS; i += 4) {   // wave-uniform trip count
            const char* src; char* dst;
            if (i < MT_ISS) {
                int off = cmt + (i << 10);
                if (off > LEN * 4 - 1024) off = LEN * 4 - 1024;
                src = mrow + off;  dst = buf + (i << 10);
            } else if (i < 2 * MT_ISS) {
                const int k = i - MT_ISS;
                int off = cmt + (k << 10);
                if (off > LEN * 4 - 1024) off = LEN * 4 - 1024;
                src = trow + off;  dst = buf + 5120 + (k << 10);
            } else {
                const int k = i - 2 * MT_ISS;
                int off = cpr + (k << 10);
                if (off > LEN * 8 - 1024) off = LEN * 8 - 1024;
                src = prow + off;  dst = buf + 10240 + (k << 10);
            }
            __builtin_amdgcn_global_load_lds(
                (const __attribute__((address_space(1))) unsigned int*)(src + lane * 16),
                (__attribute__((address_space(3))) unsigned int*)dst,
                16, 0, 0);
        }
    };

    char* cur = s_lds;
    char* nxt = s_lds + LBUF;

    float accd2[WPT] = {0.f, 0.f, 0.f, 0.f};
    float accms[WPT] = {0.f, 0.f, 0.f, 0.f};

    // prologue: stage row b0 into cur
    stage(cur, b0);
    asm volatile("s_waitcnt vmcnt(0)" ::: "memory");
    __syncthreads();

    for (int it = 0; it < bper; ++it) {
        if (it + 1 < bper) stage(nxt, b0 + it + 1);   // async prefetch

        if (j0 < WOUT) {   // only col=WBLKS-1/tid=255 is ever excluded
            RowRaw r;
            const int e0 = tid << 4;                   // 4 elems * 4B stride
            r.m0 = *(const int4*)(cur + e0);
            r.m1 = *(const int4*)(cur + e0 + 16);
            r.t0 = *(const int4*)(cur + 5120 + e0);
            r.t1 = *(const int4*)(cur + 5120 + e0 + 16);
            const int p0 = 10240 + (tid << 5);         // 4 elems * 8B stride
            r.q0 = *(const float4*)(cur + p0);
            r.q1 = *(const float4*)(cur + p0 + 16);
            r.q2 = *(const float4*)(cur + p0 + 32);
            r.q3 = *(const float4*)(cur + p0 + 48);
            RowArr a = convert_row(r);
            windows_row(a, accd2, accms);
        }

        asm volatile("s_waitcnt vmcnt(0)" ::: "memory"); // nxt fully staged
        __syncthreads();                                 // cur reads done too
        char* t = cur; cur = nxt; nxt = t;
    }

    if (j0 < WOUT) {
        *(float4*)(part_d2 + (size_t)chunk * WOUT + j0) =
            make_float4(accd2[0], accd2[1], accd2[2], accd2[3]);
        *(float4*)(part_ms + (size_t)chunk * WOUT + j0) =
            make_float4(accms[0], accms[1], accms[2], accms[3]);
    }
}

// Stage A: fold nchunks -> NCH2 chunk groups with real TLP (grid.y = NCH2).
// Also zeroes the accumulators/ticket (stream order protects stage B).
__global__ __launch_bounds__(TPB)
void bcl_chunk_reduce(const float* __restrict__ part_d2,
                      const float* __restrict__ part_ms,
                      float* __restrict__ p2_d2,
                      float* __restrict__ p2_ms,
                      double* __restrict__ accum,
                      unsigned int* __restrict__ ticket,
                      int rf) {
    if (blockIdx.x == 0 && blockIdx.y == 0 && threadIdx.x == 0) {
        accum[0] = 0.0; accum[1] = 0.0; *ticket = 0u;
    }
    const int j = blockIdx.x * blockDim.x + threadIdx.x;
    if (j >= WOUT) return;
    const int c0 = blockIdx.y * rf;
    float d2 = 0.f, ms = 0.f;
#pragma unroll 8
    for (int c = c0; c < c0 + rf; ++c) {   // ascending c: deterministic
        d2 += part_d2[(size_t)c * WOUT + j];
        ms += part_ms[(size_t)c * WOUT + j];
    }
    p2_d2[(size_t)blockIdx.y * WOUT + j] = d2;
    p2_ms[(size_t)blockIdx.y * WOUT + j] = ms;
}

// Stage B: fold NCH2 groups -> mse*valid; block-reduce to doubles; atomicAdd
// into global accumulators; last block finalizes output.
__global__ __launch_bounds__(TPB)
void bcl_window_reduce(const float* __restrict__ p2_d2,
                       const float* __restrict__ p2_ms,
                       double* __restrict__ accum,
                       unsigned int* __restrict__ ticket,
                       float* __restrict__ out,
                       int nch2) {
    const int j = blockIdx.x * blockDim.x + threadIdx.x;
    double num = 0.0, cnt = 0.0;
    if (j < WOUT) {
        float d2 = 0.f, ms = 0.f;
#pragma unroll 8
        for (int c = 0; c < nch2; ++c) {   // ascending group order
            d2 += p2_d2[(size_t)c * WOUT + j];
            ms += p2_ms[(size_t)c * WOUT + j];
        }
        if (ms > 0.f) {
            num = (double)d2 * (1.0 / (double)BATCH);
            cnt = 1.0;
        }
    }
    // wave reduce (wave = 64)
    for (int off = 32; off > 0; off >>= 1) {
        num += __shfl_down(num, off, 64);
        cnt += __shfl_down(cnt, off, 64);
    }
    __shared__ double s_num[4], s_cnt[4];
    const int lane = threadIdx.x & 63, wave = threadIdx.x >> 6;
    if (lane == 0) { s_num[wave] = num; s_cnt[wave] = cnt; }
    __syncthreads();
    if (threadIdx.x == 0) {
        double n = 0.0, c = 0.0;
        for (int wv = 0; wv < TPB / 64; ++wv) { n += s_num[wv]; c += s_cnt[wv]; }
        atomicAdd(&accum[0], n);
        atomicAdd(&accum[1], c);
        __threadfence();
        const unsigned int t = atomicAdd(ticket, 1u);
        if (t == gridDim.x - 1) {
            out[0] = (float)(accum[0] / fmax(accum[1], 1.0));
        }
    }
}

extern "C" void kernel_launch(void* const* d_in, const int* in_sizes, int n_in,
                              void* d_out, int out_size, void* d_ws, size_t ws_size,
                              hipStream_t stream) {
    const float* pred = (const float*)d_in[0];
    const int*   tgt  = (const int*)d_in[1];
    const int*   msk  = (const int*)d_in[2];
    float* out = (float*)d_out;

    // Largest batch-chunk count that fits in workspace (divides 512, pow2).
    // nchunks=128 (18.9 MB) fit in round 2's run.
    int nchunks = 128;
    while (nchunks > 2) {
        size_t need = (size_t)(nchunks + NCH2) * WOUT * 2 * sizeof(float) + 256;
        if (need <= ws_size) break;
        nchunks >>= 1;
    }
    const int bper = BATCH / nchunks;
    const int nch2 = (nchunks >= NCH2) ? NCH2 : nchunks;
    const int rf   = nchunks / nch2;

    float* part_d2 = (float*)d_ws;
    float* part_ms = part_d2 + (size_t)nchunks * WOUT;
    float* p2_d2   = part_ms + (size_t)nchunks * WOUT;
    float* p2_ms   = p2_d2   + (size_t)NCH2 * WOUT;
    // 16-byte-aligned tail region: [double num, double cnt, uint ticket]
    size_t off = ((size_t)((char*)(p2_ms + (size_t)NCH2 * WOUT) - (char*)d_ws) + 15) & ~(size_t)15;
    double* accum = (double*)((char*)d_ws + off);
    unsigned int* ticket = (unsigned int*)(accum + 2);

    dim3 g1(WBLKS, nchunks);
    bcl_partial_staged<<<g1, TPB, 0, stream>>>(pred, tgt, msk, part_d2, part_ms, bper);

    dim3 gA(RWGS, nch2);
    bcl_chunk_reduce<<<gA, TPB, 0, stream>>>(part_d2, part_ms, p2_d2, p2_ms,
                                             accum, ticket, rf);

    bcl_window_reduce<<<RWGS, TPB, 0, stream>>>(p2_d2, p2_ms, accum, ticket, out, nch2);
}

// Round 7
// 158.010 us; speedup vs baseline: 2.4661x; 1.0583x over previous
//
#include <hip/hip_runtime.h>
#include <math.h>

// Problem constants (from reference setup_inputs)
#define BATCH 512
#define LEN   16384
#define WIN   5
#define WOUT  (LEN - WIN + 1)   // 16380
#define TPB   256
#define WPT   4                  // windows per thread (WOUT % WPT == 0)
#define WPB   (TPB * WPT)        // 1024 windows per block
#define EPT   (WPT + WIN - 1)    // 8 elements per thread
#define WBLKS ((WOUT + WPB - 1) / WPB)   // 16 window-column blocks
#define RWGS  ((WOUT + TPB - 1) / TPB)   // 64 reduce blocks

// LDS tile layout (per buffer): [mask 5KB][tgt 5KB][pred 9KB] = 19456 B.
// Staged as 1KB units (64 lanes x 16B) via global_load_lds.
#define LBUF   19456
#define MT_ISS 5                 // 1KB issues for mask (and tgt): 1028*4B -> 5
#define PR_ISS 9                 // 1KB issues for pred: 1028*8B -> 9
#define N_ISS  (2 * MT_ISS + PR_ISS)   // 19 issues per row per WG

// fast reciprocal: v_rcp_f32 + 1 Newton step, ~3 insts vs ~10 for fdiv
__device__ __forceinline__ float fast_rcp(float x) {
    float r = __builtin_amdgcn_rcpf(x);
    return r * fmaf(-x, r, 2.0f);
}

struct RowRaw {
    int4   m0, m1, t0, t1;
    float4 q0, q1, q2, q3;
};
struct RowArr {
    float m[EPT], tm[EPT], pm[EPT], p2m[EPT];
};

// Same per-element arithmetic as all previously-verified rounds.
__device__ __forceinline__ RowArr convert_row(const RowRaw& r) {
    RowArr a;
    const int mi[EPT] = {r.m0.x, r.m0.y, r.m0.z, r.m0.w,
                         r.m1.x, r.m1.y, r.m1.z, r.m1.w};
    const int ti[EPT] = {r.t0.x, r.t0.y, r.t0.z, r.t0.w,
                         r.t1.x, r.t1.y, r.t1.z, r.t1.w};
    const float dx[EPT] = {r.q0.x - r.q0.y, r.q0.z - r.q0.w,
                           r.q1.x - r.q1.y, r.q1.z - r.q1.w,
                           r.q2.x - r.q2.y, r.q2.z - r.q2.w,
                           r.q3.x - r.q3.y, r.q3.z - r.q3.w};
#pragma unroll
    for (int i = 0; i < EPT; ++i) {
        const float p  = fast_rcp(1.0f + __expf(dx[i]));  // softmax[...,1]
        const float mf = (float)mi[i];
        a.m[i]   = mf;
        a.tm[i]  = (float)(ti[i] & mi[i]);  // t*m, both in {0,1}
        a.pm[i]  = p * mf;
        a.p2m[i] = p * p * mf;
    }
    return a;
}

// Same window math & ascending tap order -> bit-identical partials.
__device__ __forceinline__ void windows_row(const RowArr& a,
                                            float accd2[WPT], float accms[WPT]) {
#pragma unroll
    for (int w = 0; w < WPT; ++w) {
        float msum = 0.f, stm = 0.f, spm = 0.f, sp2m = 0.f;
#pragma unroll
        for (int k = 0; k < WIN; ++k) {
            msum += a.m[w + k];
            stm  += a.tm[w + k];
            spm  += a.pm[w + k];
            sp2m += a.p2m[w + k];
        }
        // st2m == stm since t in {0,1}
        const float denom = fmaxf(msum, 1.0f);
        const float inv   = fast_rcp(denom);
        const float pmean = spm * inv;
        const float tmean = stm * inv;
        const float pvar  = (sp2m - 2.0f * pmean * spm + pmean * pmean * msum) * inv;
        const float tvar  = (stm  - 2.0f * tmean * stm + tmean * tmean * msum) * inv;
        const float d = pvar - tvar;
        accd2[w] += d * d;
        accms[w] += msum;
    }
}

// Kernel 1: async global->LDS double-buffered staging (same verified body as
// round 6) at ONE QUARTER the workgroup count: grid (16,32) = 512 WGs, 16
// batch rows per block. Theory: duration has been pinned ~50us across every
// structure because all variants dispatched 2048 WGs (~25ns/WG dispatch
// floor); work itself is ~25us of memory traffic. 2 WGs/CU x 19KB LDS-DMA
// in flight comfortably exceeds the ~9KB/CU Little's-law requirement for
// full per-CU bandwidth, so concurrency is preserved.
__global__ __launch_bounds__(TPB)
void bcl_partial_staged(const float* __restrict__ pred,
                        const int*   __restrict__ tgt,
                        const int*   __restrict__ msk,
                        float* __restrict__ part_d2,
                        float* __restrict__ part_ms,
                        double* __restrict__ accum,
                        unsigned int* __restrict__ ticket,
                        int bper) {
    __shared__ __align__(1024) char s_lds[2 * LBUF];
    const int col   = blockIdx.x;          // 0..WBLKS-1
    const int chunk = blockIdx.y;
    const int tid   = (int)threadIdx.x;
    const int lane  = tid & 63, wid = tid >> 6;
    const int j0    = col * WPB + tid * WPT;   // first window owned
    const int b0    = chunk * bper;

    // zero global accumulators for the reduce kernel (ws re-poisoned per call)
    if (col == 0 && chunk == 0 && tid == 0) {
        accum[0] = 0.0; accum[1] = 0.0; *ticket = 0u;
    }

    const char* mbytes = (const char*)msk;
    const char* tbytes = (const char*)tgt;
    const char* pbytes = (const char*)pred;
    const int cmt = col * (WPB * 4);   // mask/tgt tile byte offset in row
    const int cpr = col * (WPB * 8);   // pred tile byte offset in row

    // Stage one batch-row's tile into LDS buffer `buf`. 1KB issues
    // (64 lanes x 16B) striped across the 4 waves; LDS dest is wave-uniform
    // (HW adds lane*16); global src is per-lane. Tail issues clamped inside
    // the row (duplicate bytes land in never-read halo slots).
    auto stage = [&](char* buf, int b) {
        const char* mrow = mbytes + (size_t)b * (LEN * 4);
        const char* trow = tbytes + (size_t)b * (LEN * 4);
        const char* prow = pbytes + (size_t)b * (LEN * 8);
        for (int i = wid; i < N_ISS; i += 4) {   // wave-uniform trip count
            const char* src; char* dst;
            if (i < MT_ISS) {
                int off = cmt + (i << 10);
                if (off > LEN * 4 - 1024) off = LEN * 4 - 1024;
                src = mrow + off;  dst = buf + (i << 10);
            } else if (i < 2 * MT_ISS) {
                const int k = i - MT_ISS;
                int off = cmt + (k << 10);
                if (off > LEN * 4 - 1024) off = LEN * 4 - 1024;
                src = trow + off;  dst = buf + 5120 + (k << 10);
            } else {
                const int k = i - 2 * MT_ISS;
                int off = cpr + (k << 10);
                if (off > LEN * 8 - 1024) off = LEN * 8 - 1024;
                src = prow + off;  dst = buf + 10240 + (k << 10);
            }
            __builtin_amdgcn_global_load_lds(
                (const __attribute__((address_space(1))) unsigned int*)(src + lane * 16),
                (__attribute__((address_space(3))) unsigned int*)dst,
                16, 0, 0);
        }
    };

    char* cur = s_lds;
    char* nxt = s_lds + LBUF;

    float accd2[WPT] = {0.f, 0.f, 0.f, 0.f};
    float accms[WPT] = {0.f, 0.f, 0.f, 0.f};

    // prologue: stage row b0 into cur
    stage(cur, b0);
    asm volatile("s_waitcnt vmcnt(0)" ::: "memory");
    __syncthreads();

    for (int it = 0; it < bper; ++it) {      // ascending b: deterministic
        if (it + 1 < bper) stage(nxt, b0 + it + 1);   // async prefetch

        if (j0 < WOUT) {   // only col=WBLKS-1/tid=255 is ever excluded
            RowRaw r;
            const int e0 = tid << 4;                   // 4 elems * 4B stride
            r.m0 = *(const int4*)(cur + e0);
            r.m1 = *(const int4*)(cur + e0 + 16);
            r.t0 = *(const int4*)(cur + 5120 + e0);
            r.t1 = *(const int4*)(cur + 5120 + e0 + 16);
            const int p0 = 10240 + (tid << 5);         // 4 elems * 8B stride
            r.q0 = *(const float4*)(cur + p0);
            r.q1 = *(const float4*)(cur + p0 + 16);
            r.q2 = *(const float4*)(cur + p0 + 32);
            r.q3 = *(const float4*)(cur + p0 + 48);
            RowArr a = convert_row(r);
            windows_row(a, accd2, accms);
        }

        asm volatile("s_waitcnt vmcnt(0)" ::: "memory"); // nxt fully staged
        __syncthreads();                                 // cur reads done too
        char* t = cur; cur = nxt; nxt = t;
    }

    if (j0 < WOUT) {
        *(float4*)(part_d2 + (size_t)chunk * WOUT + j0) =
            make_float4(accd2[0], accd2[1], accd2[2], accd2[3]);
        *(float4*)(part_ms + (size_t)chunk * WOUT + j0) =
            make_float4(accms[0], accms[1], accms[2], accms[3]);
    }
}

// Kernel 2: single direct reduce (the 1024-WG chunk_reduce stage is gone --
// its WG-dispatch floor cost more than its TLP bought). 64 WGs fold the 32
// chunks per window (ascending c, unroll 8 for load concurrency), gate
// ms>0, block-reduce to doubles, atomicAdd, last block finalizes.
__global__ __launch_bounds__(TPB)
void bcl_window_reduce(const float* __restrict__ part_d2,
                       const float* __restrict__ part_ms,
                       double* __restrict__ accum,   // [num, cnt]
                       unsigned int* __restrict__ ticket,
                       float* __restrict__ out,
                       int nchunks) {
    const int j = blockIdx.x * blockDim.x + threadIdx.x;
    double num = 0.0, cnt = 0.0;
    if (j < WOUT) {
        float d2 = 0.f, ms = 0.f;
#pragma unroll 8
        for (int c = 0; c < nchunks; ++c) {   // ascending c: deterministic
            d2 += part_d2[(size_t)c * WOUT + j];
            ms += part_ms[(size_t)c * WOUT + j];
        }
        if (ms > 0.f) {
            num = (double)d2 * (1.0 / (double)BATCH);
            cnt = 1.0;
        }
    }
    // wave reduce (wave = 64)
    for (int off = 32; off > 0; off >>= 1) {
        num += __shfl_down(num, off, 64);
        cnt += __shfl_down(cnt, off, 64);
    }
    __shared__ double s_num[4], s_cnt[4];
    const int lane = threadIdx.x & 63, wave = threadIdx.x >> 6;
    if (lane == 0) { s_num[wave] = num; s_cnt[wave] = cnt; }
    __syncthreads();
    if (threadIdx.x == 0) {
        double n = 0.0, c = 0.0;
        for (int wv = 0; wv < TPB / 64; ++wv) { n += s_num[wv]; c += s_cnt[wv]; }
        atomicAdd(&accum[0], n);
        atomicAdd(&accum[1], c);
        __threadfence();
        const unsigned int t = atomicAdd(ticket, 1u);
        if (t == gridDim.x - 1) {
            out[0] = (float)(accum[0] / fmax(accum[1], 1.0));
        }
    }
}

extern "C" void kernel_launch(void* const* d_in, const int* in_sizes, int n_in,
                              void* d_out, int out_size, void* d_ws, size_t ws_size,
                              hipStream_t stream) {
    const float* pred = (const float*)d_in[0];
    const int*   tgt  = (const int*)d_in[1];
    const int*   msk  = (const int*)d_in[2];
    float* out = (float*)d_out;

    // nchunks = 32 -> grid (16,32) = 512 WGs, bper = 16. Shrink if ws tight.
    int nchunks = 32;
    while (nchunks > 2) {
        size_t need = (size_t)nchunks * WOUT * 2 * sizeof(float) + 256;
        if (need <= ws_size) break;
        nchunks >>= 1;
    }
    const int bper = BATCH / nchunks;

    float* part_d2 = (float*)d_ws;
    float* part_ms = part_d2 + (size_t)nchunks * WOUT;
    // 16-byte-aligned tail region: [double num, double cnt, uint ticket]
    size_t off = ((size_t)((char*)(part_ms + (size_t)nchunks * WOUT) - (char*)d_ws) + 15) & ~(size_t)15;
    double* accum = (double*)((char*)d_ws + off);
    unsigned int* ticket = (unsigned int*)(accum + 2);

    dim3 g1(WBLKS, nchunks);   // 16 x 32 = 512 WGs
    bcl_partial_staged<<<g1, TPB, 0, stream>>>(pred, tgt, msk, part_d2, part_ms,
                                               accum, ticket, bper);

    bcl_window_reduce<<<RWGS, TPB, 0, stream>>>(part_d2, part_ms, accum, ticket,
                                                out, nchunks);
}

// Round 9
// 156.424 us; speedup vs baseline: 2.4911x; 1.0101x over previous
//
#include <hip/hip_runtime.h>
#include <math.h>

// Problem constants (from reference setup_inputs)
#define BATCH 512
#define LEN   16384
#define WIN   5
#define WOUT  (LEN - WIN + 1)   // 16380
#define TPB   256
#define WPT   4                  // windows per thread (WOUT % WPT == 0)
#define WPB   (TPB * WPT)        // 1024 windows per block
#define EPT   (WPT + WIN - 1)    // 8 elements per thread
#define WBLKS ((WOUT + WPB - 1) / WPB)   // 16 window-column blocks
#define RWGS  ((WOUT + TPB - 1) / TPB)   // 64 reduce blocks

// LDS tile layout (per buffer), offsets unchanged from the verified r7 body:
// [mask @0 (4112 used)][tgt @5120 (4112 used)][pred @10240 (8224 used)]
#define LBUF   19456

// fast reciprocal: v_rcp_f32 + 1 Newton step, ~3 insts vs ~10 for fdiv
__device__ __forceinline__ float fast_rcp(float x) {
    float r = __builtin_amdgcn_rcpf(x);
    return r * fmaf(-x, r, 2.0f);
}

__device__ __forceinline__ void gload16(const char* src, char* dst) {
    __builtin_amdgcn_global_load_lds(
        (const __attribute__((address_space(1))) unsigned int*)src,
        (__attribute__((address_space(3))) unsigned int*)dst,
        16, 0, 0);
}

struct RowRaw {
    int4   m0, m1, t0, t1;
    float4 q0, q1, q2, q3;
};
struct RowArr {
    float m[EPT], tm[EPT], pm[EPT], p2m[EPT];
};

// Same per-element arithmetic as all previously-verified rounds.
__device__ __forceinline__ RowArr convert_row(const RowRaw& r) {
    RowArr a;
    const int mi[EPT] = {r.m0.x, r.m0.y, r.m0.z, r.m0.w,
                         r.m1.x, r.m1.y, r.m1.z, r.m1.w};
    const int ti[EPT] = {r.t0.x, r.t0.y, r.t0.z, r.t0.w,
                         r.t1.x, r.t1.y, r.t1.z, r.t1.w};
    const float dx[EPT] = {r.q0.x - r.q0.y, r.q0.z - r.q0.w,
                           r.q1.x - r.q1.y, r.q1.z - r.q1.w,
                           r.q2.x - r.q2.y, r.q2.z - r.q2.w,
                           r.q3.x - r.q3.y, r.q3.z - r.q3.w};
#pragma unroll
    for (int i = 0; i < EPT; ++i) {
        const float p  = fast_rcp(1.0f + __expf(dx[i]));  // softmax[...,1]
        const float mf = (float)mi[i];
        a.m[i]   = mf;
        a.tm[i]  = (float)(ti[i] & mi[i]);  // t*m, both in {0,1}
        a.pm[i]  = p * mf;
        a.p2m[i] = p * p * mf;
    }
    return a;
}

// Same window math & ascending tap order -> bit-identical partials.
__device__ __forceinline__ void windows_row(const RowArr& a,
                                            float accd2[WPT], float accms[WPT]) {
#pragma unroll
    for (int w = 0; w < WPT; ++w) {
        float msum = 0.f, stm = 0.f, spm = 0.f, sp2m = 0.f;
#pragma unroll
        for (int k = 0; k < WIN; ++k) {
            msum += a.m[w + k];
            stm  += a.tm[w + k];
            spm  += a.pm[w + k];
            sp2m += a.p2m[w + k];
        }
        // st2m == stm since t in {0,1}
        const float denom = fmaxf(msum, 1.0f);
        const float inv   = fast_rcp(denom);
        const float pmean = spm * inv;
        const float tmean = stm * inv;
        const float pvar  = (sp2m - 2.0f * pmean * spm + pmean * pmean * msum) * inv;
        const float tvar  = (stm  - 2.0f * tmean * stm + tmean * tmean * msum) * inv;
        const float d = pvar - tvar;
        accd2[w] += d * d;
        accms[w] += msum;
    }
}

// Kernel 1: r7's verified double-buffered LDS-DMA body with EXACT-size
// staging: 16 full 1KB issues (exactly 4 per wave) + exec-masked 16B tail
// issues -> 16448 B/row/WG staged vs 19456 before (-15.5% device traffic:
// 163 MB -> 134.7 MB). Single-variable A/B against r7 to test the
// ~3.3 TB/s delivered-traffic ceiling theory. Sync structure, LDS layout,
// read side, and grid are byte-identical to r7's passing kernel.
__global__ __launch_bounds__(TPB)
void bcl_partial_staged(const float* __restrict__ pred,
                        const int*   __restrict__ tgt,
                        const int*   __restrict__ msk,
                        float* __restrict__ part_d2,
                        float* __restrict__ part_ms,
                        double* __restrict__ accum,
                        unsigned int* __restrict__ ticket,
                        int bper) {
    __shared__ __align__(1024) char s_lds[2 * LBUF];
    const int col   = blockIdx.x;          // 0..WBLKS-1
    const int chunk = blockIdx.y;
    const int tid   = (int)threadIdx.x;
    const int lane  = tid & 63, wid = tid >> 6;
    const int j0    = col * WPB + tid * WPT;   // first window owned
    const int b0    = chunk * bper;

    // zero global accumulators for the reduce kernel (ws re-poisoned per call)
    if (col == 0 && chunk == 0 && tid == 0) {
        accum[0] = 0.0; accum[1] = 0.0; *ticket = 0u;
    }

    const char* mbytes = (const char*)msk;
    const char* tbytes = (const char*)tgt;
    const char* pbytes = (const char*)pred;
    const int cmt = col * (WPB * 4);   // mask/tgt tile byte offset in row
    const int cpr = col * (WPB * 8);   // pred tile byte offset in row
    // Tail-issue validity: col<15 tiles need 1028 elements; col=15 ends at
    // the row boundary and no valid thread reads past element 1023 there.
    const bool mt_tail = (cmt + 4112 <= LEN * 4);
    const bool pr_tail = (cpr + 8224 <= LEN * 8);

    // Stage one batch-row's tile into LDS buffer `buf`.
    // Full issues: 1KB (64 lanes x 16B), 4 per wave; LDS dst is wave-uniform
    // (HW adds laneid*16), global src is per-lane. Tail issues: exec-masked
    // to 1-2 lanes -> stages exactly 16/32 B (per-lane transfers are
    // exec-masked; dst offset is laneid*16 so lanes 0..N-1 land contiguous).
    auto stage = [&](char* buf, int b) {
        const char* mrow = mbytes + (size_t)b * (LEN * 4);
        const char* trow = tbytes + (size_t)b * (LEN * 4);
        const char* prow = pbytes + (size_t)b * (LEN * 8);
#pragma unroll
        for (int u = 0; u < 4; ++u) {          // i = wid + 4u: 4 issues/wave
            const int i = wid + 4 * u;
            const char* src; char* dst;
            if (i < 4) {                       // mask: 4 x 1KB (0..4096)
                src = mrow + cmt + (i << 10);          dst = buf + (i << 10);
            } else if (i < 8) {                // tgt: 4 x 1KB
                const int k = i - 4;
                src = trow + cmt + (k << 10);          dst = buf + 5120 + (k << 10);
            } else {                           // pred: 8 x 1KB (0..8192)
                const int k = i - 8;
                src = prow + cpr + (k << 10);          dst = buf + 10240 + (k << 10);
            }
            gload16(src + lane * 16, dst);
        }
        // exact tails: mask bytes 4096..4112, tgt 4096..4112, pred 8192..8224
        if (wid == 0 && lane == 0 && mt_tail)
            gload16(mrow + cmt + 4096, buf + 4096);
        if (wid == 1 && lane == 0 && mt_tail)
            gload16(trow + cmt + 4096, buf + 5120 + 4096);
        if (wid == 2 && lane < 2 && pr_tail)
            gload16(prow + cpr + 8192 + lane * 16, buf + 10240 + 8192);
    };

    char* cur = s_lds;
    char* nxt = s_lds + LBUF;

    float accd2[WPT] = {0.f, 0.f, 0.f, 0.f};
    float accms[WPT] = {0.f, 0.f, 0.f, 0.f};

    // prologue: stage row b0 into cur
    stage(cur, b0);
    asm volatile("s_waitcnt vmcnt(0)" ::: "memory");
    __syncthreads();

    for (int it = 0; it < bper; ++it) {      // ascending b: deterministic
        if (it + 1 < bper) stage(nxt, b0 + it + 1);   // async prefetch

        if (j0 < WOUT) {   // only col=WBLKS-1/tid=255 is ever excluded
            RowRaw r;
            const int e0 = tid << 4;                   // 4 elems * 4B stride
            r.m0 = *(const int4*)(cur + e0);
            r.m1 = *(const int4*)(cur + e0 + 16);
            r.t0 = *(const int4*)(cur + 5120 + e0);
            r.t1 = *(const int4*)(cur + 5120 + e0 + 16);
            const int p0 = 10240 + (tid << 5);         // 4 elems * 8B stride
            r.q0 = *(const float4*)(cur + p0);
            r.q1 = *(const float4*)(cur + p0 + 16);
            r.q2 = *(const float4*)(cur + p0 + 32);
            r.q3 = *(const float4*)(cur + p0 + 48);
            RowArr a = convert_row(r);
            windows_row(a, accd2, accms);
        }

        asm volatile("s_waitcnt vmcnt(0)" ::: "memory"); // nxt fully staged
        __syncthreads();                                 // cur reads done too
        char* t = cur; cur = nxt; nxt = t;
    }

    if (j0 < WOUT) {
        *(float4*)(part_d2 + (size_t)chunk * WOUT + j0) =
            make_float4(accd2[0], accd2[1], accd2[2], accd2[3]);
        *(float4*)(part_ms + (size_t)chunk * WOUT + j0) =
            make_float4(accms[0], accms[1], accms[2], accms[3]);
    }
}

// Kernel 2: single direct reduce (r7-verified). 64 WGs fold the chunks per
// window (ascending c, unroll 8 for load concurrency), gate ms>0,
// block-reduce to doubles, atomicAdd, last block finalizes.
__global__ __launch_bounds__(TPB)
void bcl_window_reduce(const float* __restrict__ part_d2,
                       const float* __restrict__ part_ms,
                       double* __restrict__ accum,   // [num, cnt]
                       unsigned int* __restrict__ ticket,
                       float* __restrict__ out,
                       int nchunks) {
    const int j = blockIdx.x * blockDim.x + threadIdx.x;
    double num = 0.0, cnt = 0.0;
    if (j < WOUT) {
        float d2 = 0.f, ms = 0.f;
#pragma unroll 8
        for (int c = 0; c < nchunks; ++c) {   // ascending c: deterministic
            d2 += part_d2[(size_t)c * WOUT + j];
            ms += part_ms[(size_t)c * WOUT + j];
        }
        if (ms > 0.f) {
            num = (double)d2 * (1.0 / (double)BATCH);
            cnt = 1.0;
        }
    }
    // wave reduce (wave = 64)
    for (int off = 32; off > 0; off >>= 1) {
        num += __shfl_down(num, off, 64);
        cnt += __shfl_down(cnt, off, 64);
    }
    __shared__ double s_num[4], s_cnt[4];
    const int lane = threadIdx.x & 63, wave = threadIdx.x >> 6;
    if (lane == 0) { s_num[wave] = num; s_cnt[wave] = cnt; }
    __syncthreads();
    if (threadIdx.x == 0) {
        double n = 0.0, c = 0.0;
        for (int wv = 0; wv < TPB / 64; ++wv) { n += s_num[wv]; c += s_cnt[wv]; }
        atomicAdd(&accum[0], n);
        atomicAdd(&accum[1], c);
        __threadfence();
        const unsigned int t = atomicAdd(ticket, 1u);
        if (t == gridDim.x - 1) {
            out[0] = (float)(accum[0] / fmax(accum[1], 1.0));
        }
    }
}

extern "C" void kernel_launch(void* const* d_in, const int* in_sizes, int n_in,
                              void* d_out, int out_size, void* d_ws, size_t ws_size,
                              hipStream_t stream) {
    const float* pred = (const float*)d_in[0];
    const int*   tgt  = (const int*)d_in[1];
    const int*   msk  = (const int*)d_in[2];
    float* out = (float*)d_out;

    // nchunks = 32 -> grid (16,32) = 512 WGs, bper = 16 (r7-verified config).
    int nchunks = 32;
    while (nchunks > 2) {
        size_t need = (size_t)nchunks * WOUT * 2 * sizeof(float) + 256;
        if (need <= ws_size) break;
        nchunks >>= 1;
    }
    const int bper = BATCH / nchunks;

    float* part_d2 = (float*)d_ws;
    float* part_ms = part_d2 + (size_t)nchunks * WOUT;
    // 16-byte-aligned tail region: [double num, double cnt, uint ticket]
    size_t off = ((size_t)((char*)(part_ms + (size_t)nchunks * WOUT) - (char*)d_ws) + 15) & ~(size_t)15;
    double* accum = (double*)((char*)d_ws + off);
    unsigned int* ticket = (unsigned int*)(accum + 2);

    dim3 g1(WBLKS, nchunks);   // 16 x 32 = 512 WGs
    bcl_partial_staged<<<g1, TPB, 0, stream>>>(pred, tgt, msk, part_d2, part_ms,
                                               accum, ticket, bper);

    bcl_window_reduce<<<RWGS, TPB, 0, stream>>>(part_d2, part_ms, accum, ticket,
                                                out, nchunks);
}